// Round 6
// baseline (264.929 us; speedup 1.0000x reference)
//
#include <hip/hip_runtime.h>

#define HID 256
#define PROJ 256
#define DYN 64
#define HWD 6400
#define BSZ 16
#define NQ 100
#define HH 80
#define WW 80

typedef unsigned short u16;
typedef u16 u16x8 __attribute__((ext_vector_type(8)));
typedef __bf16 bf16x8 __attribute__((ext_vector_type(8)));
typedef float f32x4 __attribute__((ext_vector_type(4)));

__device__ __forceinline__ float bf2f(u16 h) {
    union { unsigned u; float f; } c; c.u = ((unsigned)h) << 16; return c.f;
}
__device__ __forceinline__ u16 f2bf(float f) {
    union { float f; unsigned u; } c; c.f = f;
    return (u16)((c.u + 0x7FFFu + ((c.u >> 16) & 1u)) >> 16);
}

// ---------------------------------------------------------------------------
// K1 v3 (unchanged): 1024 thr, 4-way K-split, pinned weight batches.
// ---------------------------------------------------------------------------
__global__ __launch_bounds__(1024, 1) void kpre(
    const float* __restrict__ support,   // [100][16][256] f32
    const float* __restrict__ Wq, const float* __restrict__ bq,
    const float* __restrict__ Ws, const float* __restrict__ bsp,
    const float* __restrict__ W1, const float* __restrict__ b1,
    const float* __restrict__ W2, const float* __restrict__ b2,
    u16* __restrict__ pack, float* __restrict__ cvec)
{
    const int c = blockIdx.x;   // n-chunk (8 n each), 0..13
    const int b = blockIdx.y;   // 0..15
    const int t = threadIdx.x;  // 0..1023

    __shared__ __align__(16) float sf_t[HID][8];
    __shared__ __align__(16) float part[4][8][256];
    __shared__ __align__(16) float fsp[8][PROJ];
    __shared__ __align__(16) float hidp[2][8][DYN];
    __shared__ __align__(16) float hid[8][DYN];
    __shared__ __align__(16) float fsf_t[PROJ][8];
    __shared__ float cacc[8][4];

    const int g = t >> 8;
    const int p = t & 255;

    // step 1: load 8 support rows -> transposed LDS
    {
        const int nl = t >> 7;
        const int i0 = (t & 127) * 2;
        const int n = c * 8 + nl;
        float v0 = 0.f, v1 = 0.f;
        if (n < NQ) {
            const float* sp = support + (size_t)n * (BSZ * HID) + (size_t)b * HID + i0;
            const float2 a = *reinterpret_cast<const float2*>(sp);
            v0 = a.x; v1 = a.y;
        }
        sf_t[i0][nl] = v0;
        sf_t[i0 + 1][nl] = v1;
    }
    __syncthreads();

    // step 2: fs_proj partials
    {
        float acc[8];
        #pragma unroll
        for (int n = 0; n < 8; ++n) acc[n] = 0.f;
        const int ibase = g * 64;
        float w[64];
        #pragma unroll
        for (int j = 0; j < 64; ++j)
            w[j] = Ws[(size_t)(ibase + j) * PROJ + p];
        __builtin_amdgcn_sched_barrier(0);
        #pragma unroll
        for (int j = 0; j < 64; ++j) {
            const f32x4 s0 = *reinterpret_cast<const f32x4*>(&sf_t[ibase + j][0]);
            const f32x4 s1 = *reinterpret_cast<const f32x4*>(&sf_t[ibase + j][4]);
            acc[0] += s0[0] * w[j]; acc[1] += s0[1] * w[j];
            acc[2] += s0[2] * w[j]; acc[3] += s0[3] * w[j];
            acc[4] += s1[0] * w[j]; acc[5] += s1[1] * w[j];
            acc[6] += s1[2] * w[j]; acc[7] += s1[3] * w[j];
        }
        #pragma unroll
        for (int n = 0; n < 8; ++n) part[g][n][p] = acc[n];
    }
    __syncthreads();
    {
        const int na = t >> 8;
        const float bb = bsp[p];
        #pragma unroll
        for (int k = 0; k < 2; ++k) {
            const int n = na + k * 4;
            fsp[n][p] = part[0][n][p] + part[1][n][p] + part[2][n][p] + part[3][n][p] + bb;
        }
    }
    __syncthreads();

    // step 3: hidden
    {
        const int ph = t >> 9;
        const int n = (t >> 6) & 7;
        const int d = t & 63;
        float a = 0.f;
        const int pb0 = ph * 128;
        #pragma unroll
        for (int pb = 0; pb < 128; pb += 64) {
            float w[64];
            #pragma unroll
            for (int j = 0; j < 64; ++j)
                w[j] = W1[(size_t)(pb0 + pb + j) * DYN + d];
            __builtin_amdgcn_sched_barrier(0);
            #pragma unroll
            for (int j = 0; j < 64; j += 4) {
                const f32x4 s = *reinterpret_cast<const f32x4*>(&fsp[n][pb0 + pb + j]);
                a += s[0] * w[j] + s[1] * w[j + 1] + s[2] * w[j + 2] + s[3] * w[j + 3];
            }
        }
        hidp[ph][n][d] = a;
    }
    __syncthreads();
    if (t < 512) {
        const int n = t >> 6, d = t & 63;
        const float a = hidp[0][n][d] + hidp[1][n][d] + b1[d];
        hid[n][d] = a > 0.f ? a : 0.f;
    }
    __syncthreads();

    // step 4: pattern -> fs_feat + c partials
    {
        const int nh = t >> 8;
        const int n0 = nh * 2, n1 = nh * 2 + 1;
        const float bqv = bq[p];
        const float b2v = b2[p];
        float w[64];
        #pragma unroll
        for (int d = 0; d < 64; ++d) w[d] = W2[(size_t)d * PROJ + p];
        __builtin_amdgcn_sched_barrier(0);
        float a0 = 0.f, a1 = 0.f;
        #pragma unroll
        for (int d0 = 0; d0 < 64; d0 += 4) {
            const f32x4 h0 = *reinterpret_cast<const f32x4*>(&hid[n0][d0]);
            const f32x4 h1 = *reinterpret_cast<const f32x4*>(&hid[n1][d0]);
            a0 += h0[0] * w[d0] + h0[1] * w[d0 + 1] + h0[2] * w[d0 + 2] + h0[3] * w[d0 + 3];
            a1 += h1[0] * w[d0] + h1[1] * w[d0 + 1] + h1[2] * w[d0 + 2] + h1[3] * w[d0 + 3];
        }
        const float pat0 = tanhf(a0 + b2v);
        const float pat1 = tanhf(a1 + b2v);
        const float ff0 = (pat0 + 1.f) * fsp[n0][p];
        const float ff1 = (pat1 + 1.f) * fsp[n1][p];
        *reinterpret_cast<float2*>(&fsf_t[p][n0]) = make_float2(ff0, ff1);
        float cp0 = bqv * ff0, cp1 = bqv * ff1;
        for (int off = 32; off > 0; off >>= 1) {
            cp0 += __shfl_down(cp0, off);
            cp1 += __shfl_down(cp1, off);
        }
        const int lane = t & 63;
        const int ps = (t >> 6) & 3;
        if (lane == 0) { cacc[n0][ps] = cp0; cacc[n1][ps] = cp1; }
    }
    __syncthreads();
    if (t < 8) {
        const int n = c * 8 + t;
        if (n < NQ) cvec[b * NQ + n] = cacc[t][0] + cacc[t][1] + cacc[t][2] + cacc[t][3];
    }

    // step 5: Gt[n][h]
    {
        const int h = p;
        float acc[8];
        #pragma unroll
        for (int n = 0; n < 8; ++n) acc[n] = 0.f;
        const int pbase = g * 64;
        f32x4 wv4[16];
        #pragma unroll
        for (int k = 0; k < 16; ++k)
            wv4[k] = *reinterpret_cast<const f32x4*>(Wq + (size_t)h * PROJ + pbase + k * 4);
        __builtin_amdgcn_sched_barrier(0);
        #pragma unroll
        for (int k = 0; k < 16; ++k) {
            #pragma unroll
            for (int m = 0; m < 4; ++m) {
                const int pp = pbase + k * 4 + m;
                const float w = wv4[k][m];
                const f32x4 f0 = *reinterpret_cast<const f32x4*>(&fsf_t[pp][0]);
                const f32x4 f1 = *reinterpret_cast<const f32x4*>(&fsf_t[pp][4]);
                acc[0] += f0[0] * w; acc[1] += f0[1] * w;
                acc[2] += f0[2] * w; acc[3] += f0[3] * w;
                acc[4] += f1[0] * w; acc[5] += f1[1] * w;
                acc[6] += f1[2] * w; acc[7] += f1[3] * w;
            }
        }
        #pragma unroll
        for (int n = 0; n < 8; ++n) part[g][n][h] = acc[n];
    }
    __syncthreads();

    // final reduce + hi/lo bf16 pack
    {
        const int h = p;
        const int na = t >> 8;
        const int ks = h >> 5, quad = (h >> 3) & 3, j = h & 7;
        const int nt = c >> 1;
        #pragma unroll
        for (int k = 0; k < 2; ++k) {
            const int nl = na + k * 4;
            const int n = c * 8 + nl;
            float f = part[0][nl][h] + part[1][nl][h] + part[2][nl][h] + part[3][nl][h];
            if (n >= NQ) f = 0.f;
            const u16 hi = f2bf(f);
            const u16 lo = f2bf(f - bf2f(hi));
            const int nit = (c & 1) * 8 + nl;
            const int lane2 = quad * 16 + nit;
            const size_t base = ((((size_t)b * 2 + 0) * 8 + ks) * 8 + nt) * 512 + lane2 * 8 + j;
            pack[base] = hi;
            pack[base + (size_t)8 * 8 * 512] = lo;
        }
    }
}

// ---------------------------------------------------------------------------
// K2 v9: BARRIER-FREE. R3-R5 post-mortem: every structure with a per-ks
// __syncthreads stalled identically (wave lifetime ~20us vs ~1us of work;
// the barrier's vmcnt(0) drain gang-stalls all 4 waves x 8 iterations).
// LDS staging only de-duplicated B-reads across 4 waves -- but pack is L2-
// resident (128KB/b shared by 100 blocks); redundancy is cheap, sync isn't.
// New shape: 1-wave blocks (64thr), no LDS, no barriers. B-fragments via
// asm-volatile global_load_dwordx4 (un-sinkable) in a half-ks pipeline with
// counted s_waitcnt vmcnt(7) (T4: never drain to 0 in-loop) + sched_barrier
// after each wait (rule #18). L2 latency hidden by MLP (7 in flight) x TLP
// (~3 waves/SIMD at ~140 VGPR, launch_bounds(64,3)).
// ---------------------------------------------------------------------------
__global__ __launch_bounds__(64, 3) void ksim(
    const float* __restrict__ qf,    // [6400][16][256] f32
    const u16* __restrict__ pack,
    const float* __restrict__ cvec,
    float* __restrict__ sim)         // -> out + 3200, [16][100][6400] f32
{
    const int bx = blockIdx.x;  // 0..399 (16 rows each)
    const int b  = blockIdx.y;  // 0..15
    const int lane = threadIdx.x;    // 0..63
    const int quad = lane >> 4, l16 = lane & 15;

    f32x4 acc[7];
    #pragma unroll
    for (int nt = 0; nt < 7; ++nt) acc[nt] = (f32x4){0.f, 0.f, 0.f, 0.f};

    const int row = bx * 16 + l16;
    const float* ap = qf + (size_t)row * (BSZ * HID) + b * HID + quad * 8;
    // pack slice for this b: [s(2)][ks(8)][nt(8)][lane(64)][8 u16]
    const u16* pb = pack + (size_t)b * 65536 + (size_t)lane * 8;

    // ---- prologue: ALL 16 A loads + wait in ONE asm block ----
    f32x4 af[16];
    {
        const float* p0 = ap + 0 * 32;
        const float* p1 = ap + 1 * 32;
        const float* p2 = ap + 2 * 32;
        const float* p3 = ap + 3 * 32;
        const float* p4 = ap + 4 * 32;
        const float* p5 = ap + 5 * 32;
        const float* p6 = ap + 6 * 32;
        const float* p7 = ap + 7 * 32;
        asm volatile(
            "global_load_dwordx4 %0, %16, off\n\t"
            "global_load_dwordx4 %1, %16, off offset:16\n\t"
            "global_load_dwordx4 %2, %17, off\n\t"
            "global_load_dwordx4 %3, %17, off offset:16\n\t"
            "global_load_dwordx4 %4, %18, off\n\t"
            "global_load_dwordx4 %5, %18, off offset:16\n\t"
            "global_load_dwordx4 %6, %19, off\n\t"
            "global_load_dwordx4 %7, %19, off offset:16\n\t"
            "global_load_dwordx4 %8, %20, off\n\t"
            "global_load_dwordx4 %9, %20, off offset:16\n\t"
            "global_load_dwordx4 %10, %21, off\n\t"
            "global_load_dwordx4 %11, %21, off offset:16\n\t"
            "global_load_dwordx4 %12, %22, off\n\t"
            "global_load_dwordx4 %13, %22, off offset:16\n\t"
            "global_load_dwordx4 %14, %23, off\n\t"
            "global_load_dwordx4 %15, %23, off offset:16\n\t"
            "s_waitcnt vmcnt(0)"
            : "=&v"(af[0]), "=&v"(af[1]), "=&v"(af[2]), "=&v"(af[3]),
              "=&v"(af[4]), "=&v"(af[5]), "=&v"(af[6]), "=&v"(af[7]),
              "=&v"(af[8]), "=&v"(af[9]), "=&v"(af[10]), "=&v"(af[11]),
              "=&v"(af[12]), "=&v"(af[13]), "=&v"(af[14]), "=&v"(af[15])
            : "v"(p0), "v"(p1), "v"(p2), "v"(p3),
              "v"(p4), "v"(p5), "v"(p6), "v"(p7));
    }

    // convert A to hi/lo bf16 fragments (af dies here)
    bf16x8 Ahi[8], Alo[8];
    #pragma unroll
    for (int ks = 0; ks < 8; ++ks) {
        #pragma unroll
        for (int j = 0; j < 4; ++j) {
            const float v0 = af[2 * ks][j];
            const __bf16 h0 = (__bf16)v0;
            Ahi[ks][j] = h0; Alo[ks][j] = (__bf16)(v0 - (float)h0);
            const float v1 = af[2 * ks + 1][j];
            const __bf16 h1 = (__bf16)v1;
            Ahi[ks][4 + j] = h1; Alo[ks][4 + j] = (__bf16)(v1 - (float)h1);
        }
    }

    // 7 B-fragment loads in one un-splittable asm batch (nt 0..3 off A, 4..6 off B)
    #define ISSUE7(F, PA, PB)                                                   \
        asm volatile(                                                           \
            "global_load_dwordx4 %0, %7, off\n\t"                               \
            "global_load_dwordx4 %1, %7, off offset:1024\n\t"                   \
            "global_load_dwordx4 %2, %7, off offset:2048\n\t"                   \
            "global_load_dwordx4 %3, %7, off offset:3072\n\t"                   \
            "global_load_dwordx4 %4, %8, off\n\t"                               \
            "global_load_dwordx4 %5, %8, off offset:1024\n\t"                   \
            "global_load_dwordx4 %6, %8, off offset:2048"                       \
            : "=&v"((F)[0]), "=&v"((F)[1]), "=&v"((F)[2]), "=&v"((F)[3]),       \
              "=&v"((F)[4]), "=&v"((F)[5]), "=&v"((F)[6])                       \
            : "v"(PA), "v"(PB))
    #define WAIT7 do { asm volatile("s_waitcnt vmcnt(7)" ::: "memory");         \
                       __builtin_amdgcn_sched_barrier(0); } while (0)

    f32x4 fH[7], fL[7];

    // issue hi(ks=0)
    {
        const u16* hA = pb;
        ISSUE7(fH, hA, hA + 2048);
    }

    #define KS_BODY(KS)                                                          \
    {                                                                            \
        const u16* lA = pb + 32768 + (KS) * 4096;                                \
        ISSUE7(fL, lA, lA + 2048);          /* outstanding: hi(KS)+lo(KS)=14 */  \
        WAIT7;                              /* hi(KS) done */                    \
        _Pragma("unroll")                                                        \
        for (int nt = 0; nt < 7; ++nt) {                                         \
            const bf16x8 bh = __builtin_bit_cast(bf16x8, fH[nt]);                \
            acc[nt] = __builtin_amdgcn_mfma_f32_16x16x32_bf16(Ahi[KS], bh, acc[nt], 0, 0, 0); \
            acc[nt] = __builtin_amdgcn_mfma_f32_16x16x32_bf16(Alo[KS], bh, acc[nt], 0, 0, 0); \
        }                                                                        \
        const u16* hA = pb + ((KS) + 1) * 4096;  /* KS=7: in-bounds dummy */     \
        ISSUE7(fH, hA, hA + 2048);          /* outstanding: lo(KS)+hi(KS+1) */   \
        WAIT7;                              /* lo(KS) done */                    \
        _Pragma("unroll")                                                        \
        for (int nt = 0; nt < 7; ++nt) {                                         \
            const bf16x8 bl = __builtin_bit_cast(bf16x8, fL[nt]);                \
            acc[nt] = __builtin_amdgcn_mfma_f32_16x16x32_bf16(Ahi[KS], bl, acc[nt], 0, 0, 0); \
        }                                                                        \
    }

    KS_BODY(0) KS_BODY(1) KS_BODY(2) KS_BODY(3)
    KS_BODY(4) KS_BODY(5) KS_BODY(6) KS_BODY(7)

    #undef KS_BODY
    #undef WAIT7
    #undef ISSUE7

    // drain the trailing dummy loads before the epilogue's own VMEM
    asm volatile("s_waitcnt vmcnt(0)" ::: "memory");
    __builtin_amdgcn_sched_barrier(0);

    // epilogue: D row (k-dim) = quad*4 + r, col (n) = l16
    const int kbase = bx * 16 + quad * 4;
    #pragma unroll
    for (int nt = 0; nt < 7; ++nt) {
        const int n = nt * 16 + l16;
        if (n >= NQ) continue;
        const float cadd = cvec[b * NQ + n];
        f32x4 o = acc[nt];
        o[0] += cadd; o[1] += cadd; o[2] += cadd; o[3] += cadd;
        *reinterpret_cast<f32x4*>(sim + (size_t)(b * NQ + n) * HWD + kbase) = o;
    }
}

// ---------------------------------------------------------------------------
// K3 v6 (unchanged): two waves per (b,n) row, pinned load batch.
// ---------------------------------------------------------------------------
__global__ __launch_bounds__(128, 2) void kfin(
    const float* __restrict__ sim,   // out + 3200
    float* __restrict__ out)         // f32 outputs, concatenated
{
    const int bn = blockIdx.x;       // 0..1599
    const int w = threadIdx.x >> 6;  // 0..1
    const int lane = threadIdx.x & 63;
    const float* src = sim + (size_t)bn * HWD;

    __shared__ float redf[2][8];

    const int base = w ? 12 : 0;
    const int cnt  = w ? 13 : 12;

    f32x4 v[13];
    #pragma unroll
    for (int j = 0; j < 13; ++j)
        if (j < cnt)
            v[j] = *reinterpret_cast<const f32x4*>(src + (base + j) * 256 + lane * 4);
    __builtin_amdgcn_sched_barrier(0);

    // phase A: local max / first-occurrence argmax, then global via LDS
    float bv = -3.4e38f; int bi = 0x7FFFFFFF;
    #pragma unroll
    for (int j = 0; j < 13; ++j) {
        if (j < cnt) {
            #pragma unroll
            for (int k = 0; k < 4; ++k) {
                if (v[j][k] > bv) { bv = v[j][k]; bi = (base + j) * 256 + lane * 4 + k; }
            }
        }
    }
    #pragma unroll
    for (int m = 1; m < 64; m <<= 1) {
        const float ov = __shfl_xor(bv, m);
        const int oi = __shfl_xor(bi, m);
        if (ov > bv || (ov == bv && oi < bi)) { bv = ov; bi = oi; }
    }
    if (lane == 0) { redf[w][0] = bv; redf[w][1] = __int_as_float(bi); }
    __syncthreads();
    {
        const float v0 = redf[0][0], v1 = redf[1][0];
        const int i0 = __float_as_int(redf[0][1]), i1 = __float_as_int(redf[1][1]);
        if (v1 > v0 || (v1 == v0 && i1 < i0)) { bv = v1; bi = i1; }
        else { bv = v0; bi = i0; }
    }
    const int xc = bi % WW, yc = bi / WW;

    // phase B: exp sums + 3x3 window sums
    float s1 = 0.f, sx = 0.f, sy = 0.f;
    float wl = 0.f, wx = 0.f, wyv = 0.f;
    const int g0 = base * 256 + lane * 4;
    int x = g0 % WW, y = g0 / WW;
    #pragma unroll
    for (int j = 0; j < 13; ++j) {
        if (j < cnt) {
            #pragma unroll
            for (int k = 0; k < 4; ++k) {
                int xe = x + k, ye = y;
                if (xe >= WW) { xe -= WW; ye += 1; }
                const float e = __expf(v[j][k] - bv);
                const float fx = (float)xe + 0.5f;
                const float fy = (float)ye + 0.5f;
                s1 += e; sx += e * fx; sy += e * fy;
                const int dx = xe - xc, dy = ye - yc;
                const bool inw = (dx >= -1 && dx <= 1 && dy >= -1 && dy <= 1);
                const float ew = inw ? e : 0.f;
                wl += ew; wx += ew * fx; wyv += ew * fy;
            }
        }
        x += 16; y += 3;
        if (x >= WW) { x -= WW; y += 1; }
    }
    #pragma unroll
    for (int m = 1; m < 64; m <<= 1) {
        s1 += __shfl_xor(s1, m);
        sx += __shfl_xor(sx, m);
        sy += __shfl_xor(sy, m);
        wl += __shfl_xor(wl, m);
        wx += __shfl_xor(wx, m);
        wyv += __shfl_xor(wyv, m);
    }
    if (lane == 0) {
        redf[w][2] = s1; redf[w][3] = sx; redf[w][4] = sy;
        redf[w][5] = wl; redf[w][6] = wx; redf[w][7] = wyv;
    }
    __syncthreads();

    if (w == 0 && lane == 0) {
        const float S1 = redf[0][2] + redf[1][2];
        const float SX = redf[0][3] + redf[1][3];
        const float SY = redf[0][4] + redf[1][4];
        const float WL = redf[0][5] + redf[1][5];
        const float WX = redf[0][6] + redf[1][6];
        const float WY = redf[0][7] + redf[1][7];
        const float invS = 1.f / S1;
        out[(size_t)bn * 2 + 0] = SX * invS / (float)WW;
        out[(size_t)bn * 2 + 1] = SY * invS / (float)HH;
        const float den = WL + 1e-10f * S1;
        const size_t pbase = 3200 + (size_t)BSZ * NQ * HWD;
        out[pbase + (size_t)bn * 2 + 0] = WX / den / (float)WW;
        out[pbase + (size_t)bn * 2 + 1] = WY / den / (float)HH;
    }
}

extern "C" void kernel_launch(void* const* d_in, const int* in_sizes, int n_in,
                              void* d_out, int out_size, void* d_ws, size_t ws_size,
                              hipStream_t stream) {
    const float* qf  = (const float*)d_in[0];   // query_feat  [6400][16][256] f32
    const float* sf  = (const float*)d_in[1];   // support_feat[100][16][256] f32
    // d_in[2], d_in[3] = h, w (fixed 80x80)
    const float* Wq  = (const float*)d_in[4];
    const float* bq  = (const float*)d_in[5];
    const float* Ws  = (const float*)d_in[6];
    const float* bsp = (const float*)d_in[7];
    const float* W1  = (const float*)d_in[8];
    const float* b1  = (const float*)d_in[9];
    const float* W2  = (const float*)d_in[10];
    const float* b2  = (const float*)d_in[11];

    u16*   pack  = (u16*)d_ws;                         // 2,097,152 B
    float* cvec  = (float*)((char*)d_ws + 2097152);    //     6,400 B
    float* out   = (float*)d_out;
    float* sim   = out + 3200;                         // similarity region, f32

    kpre<<<dim3(14, 16), 1024, 0, stream>>>(sf, Wq, bq, Ws, bsp, W1, b1, W2, b2, pack, cvec);
    ksim<<<dim3(400, 16), 64, 0, stream>>>(qf, pack, cvec, sim);
    kfin<<<1600, 64 * 2, 0, stream>>>(sim, out);
}

// Round 7
// 250.153 us; speedup vs baseline: 1.0591x; 1.0591x over previous
//
#include <hip/hip_runtime.h>

#define HID 256
#define PROJ 256
#define DYN 64
#define HWD 6400
#define BSZ 16
#define NQ 100
#define HH 80
#define WW 80

typedef unsigned short u16;
typedef u16 u16x8 __attribute__((ext_vector_type(8)));
typedef __bf16 bf16x8 __attribute__((ext_vector_type(8)));
typedef float f32x4 __attribute__((ext_vector_type(4)));

__device__ __forceinline__ float bf2f(u16 h) {
    union { unsigned u; float f; } c; c.u = ((unsigned)h) << 16; return c.f;
}
__device__ __forceinline__ u16 f2bf(float f) {
    union { float f; unsigned u; } c; c.f = f;
    return (u16)((c.u + 0x7FFFu + ((c.u >> 16) & 1u)) >> 16);
}

// ---------------------------------------------------------------------------
// K1 v3 (unchanged): 1024 thr, 4-way K-split, pinned weight batches.
// ---------------------------------------------------------------------------
__global__ __launch_bounds__(1024, 1) void kpre(
    const float* __restrict__ support,   // [100][16][256] f32
    const float* __restrict__ Wq, const float* __restrict__ bq,
    const float* __restrict__ Ws, const float* __restrict__ bsp,
    const float* __restrict__ W1, const float* __restrict__ b1,
    const float* __restrict__ W2, const float* __restrict__ b2,
    u16* __restrict__ pack, float* __restrict__ cvec)
{
    const int c = blockIdx.x;   // n-chunk (8 n each), 0..13
    const int b = blockIdx.y;   // 0..15
    const int t = threadIdx.x;  // 0..1023

    __shared__ __align__(16) float sf_t[HID][8];
    __shared__ __align__(16) float part[4][8][256];
    __shared__ __align__(16) float fsp[8][PROJ];
    __shared__ __align__(16) float hidp[2][8][DYN];
    __shared__ __align__(16) float hid[8][DYN];
    __shared__ __align__(16) float fsf_t[PROJ][8];
    __shared__ float cacc[8][4];

    const int g = t >> 8;
    const int p = t & 255;

    // step 1: load 8 support rows -> transposed LDS
    {
        const int nl = t >> 7;
        const int i0 = (t & 127) * 2;
        const int n = c * 8 + nl;
        float v0 = 0.f, v1 = 0.f;
        if (n < NQ) {
            const float* sp = support + (size_t)n * (BSZ * HID) + (size_t)b * HID + i0;
            const float2 a = *reinterpret_cast<const float2*>(sp);
            v0 = a.x; v1 = a.y;
        }
        sf_t[i0][nl] = v0;
        sf_t[i0 + 1][nl] = v1;
    }
    __syncthreads();

    // step 2: fs_proj partials
    {
        float acc[8];
        #pragma unroll
        for (int n = 0; n < 8; ++n) acc[n] = 0.f;
        const int ibase = g * 64;
        float w[64];
        #pragma unroll
        for (int j = 0; j < 64; ++j)
            w[j] = Ws[(size_t)(ibase + j) * PROJ + p];
        __builtin_amdgcn_sched_barrier(0);
        #pragma unroll
        for (int j = 0; j < 64; ++j) {
            const f32x4 s0 = *reinterpret_cast<const f32x4*>(&sf_t[ibase + j][0]);
            const f32x4 s1 = *reinterpret_cast<const f32x4*>(&sf_t[ibase + j][4]);
            acc[0] += s0[0] * w[j]; acc[1] += s0[1] * w[j];
            acc[2] += s0[2] * w[j]; acc[3] += s0[3] * w[j];
            acc[4] += s1[0] * w[j]; acc[5] += s1[1] * w[j];
            acc[6] += s1[2] * w[j]; acc[7] += s1[3] * w[j];
        }
        #pragma unroll
        for (int n = 0; n < 8; ++n) part[g][n][p] = acc[n];
    }
    __syncthreads();
    {
        const int na = t >> 8;
        const float bb = bsp[p];
        #pragma unroll
        for (int k = 0; k < 2; ++k) {
            const int n = na + k * 4;
            fsp[n][p] = part[0][n][p] + part[1][n][p] + part[2][n][p] + part[3][n][p] + bb;
        }
    }
    __syncthreads();

    // step 3: hidden
    {
        const int ph = t >> 9;
        const int n = (t >> 6) & 7;
        const int d = t & 63;
        float a = 0.f;
        const int pb0 = ph * 128;
        #pragma unroll
        for (int pb = 0; pb < 128; pb += 64) {
            float w[64];
            #pragma unroll
            for (int j = 0; j < 64; ++j)
                w[j] = W1[(size_t)(pb0 + pb + j) * DYN + d];
            __builtin_amdgcn_sched_barrier(0);
            #pragma unroll
            for (int j = 0; j < 64; j += 4) {
                const f32x4 s = *reinterpret_cast<const f32x4*>(&fsp[n][pb0 + pb + j]);
                a += s[0] * w[j] + s[1] * w[j + 1] + s[2] * w[j + 2] + s[3] * w[j + 3];
            }
        }
        hidp[ph][n][d] = a;
    }
    __syncthreads();
    if (t < 512) {
        const int n = t >> 6, d = t & 63;
        const float a = hidp[0][n][d] + hidp[1][n][d] + b1[d];
        hid[n][d] = a > 0.f ? a : 0.f;
    }
    __syncthreads();

    // step 4: pattern -> fs_feat + c partials
    {
        const int nh = t >> 8;
        const int n0 = nh * 2, n1 = nh * 2 + 1;
        const float bqv = bq[p];
        const float b2v = b2[p];
        float w[64];
        #pragma unroll
        for (int d = 0; d < 64; ++d) w[d] = W2[(size_t)d * PROJ + p];
        __builtin_amdgcn_sched_barrier(0);
        float a0 = 0.f, a1 = 0.f;
        #pragma unroll
        for (int d0 = 0; d0 < 64; d0 += 4) {
            const f32x4 h0 = *reinterpret_cast<const f32x4*>(&hid[n0][d0]);
            const f32x4 h1 = *reinterpret_cast<const f32x4*>(&hid[n1][d0]);
            a0 += h0[0] * w[d0] + h0[1] * w[d0 + 1] + h0[2] * w[d0 + 2] + h0[3] * w[d0 + 3];
            a1 += h1[0] * w[d0] + h1[1] * w[d0 + 1] + h1[2] * w[d0 + 2] + h1[3] * w[d0 + 3];
        }
        const float pat0 = tanhf(a0 + b2v);
        const float pat1 = tanhf(a1 + b2v);
        const float ff0 = (pat0 + 1.f) * fsp[n0][p];
        const float ff1 = (pat1 + 1.f) * fsp[n1][p];
        *reinterpret_cast<float2*>(&fsf_t[p][n0]) = make_float2(ff0, ff1);
        float cp0 = bqv * ff0, cp1 = bqv * ff1;
        for (int off = 32; off > 0; off >>= 1) {
            cp0 += __shfl_down(cp0, off);
            cp1 += __shfl_down(cp1, off);
        }
        const int lane = t & 63;
        const int ps = (t >> 6) & 3;
        if (lane == 0) { cacc[n0][ps] = cp0; cacc[n1][ps] = cp1; }
    }
    __syncthreads();
    if (t < 8) {
        const int n = c * 8 + t;
        if (n < NQ) cvec[b * NQ + n] = cacc[t][0] + cacc[t][1] + cacc[t][2] + cacc[t][3];
    }

    // step 5: Gt[n][h]
    {
        const int h = p;
        float acc[8];
        #pragma unroll
        for (int n = 0; n < 8; ++n) acc[n] = 0.f;
        const int pbase = g * 64;
        f32x4 wv4[16];
        #pragma unroll
        for (int k = 0; k < 16; ++k)
            wv4[k] = *reinterpret_cast<const f32x4*>(Wq + (size_t)h * PROJ + pbase + k * 4);
        __builtin_amdgcn_sched_barrier(0);
        #pragma unroll
        for (int k = 0; k < 16; ++k) {
            #pragma unroll
            for (int m = 0; m < 4; ++m) {
                const int pp = pbase + k * 4 + m;
                const float w = wv4[k][m];
                const f32x4 f0 = *reinterpret_cast<const f32x4*>(&fsf_t[pp][0]);
                const f32x4 f1 = *reinterpret_cast<const f32x4*>(&fsf_t[pp][4]);
                acc[0] += f0[0] * w; acc[1] += f0[1] * w;
                acc[2] += f0[2] * w; acc[3] += f0[3] * w;
                acc[4] += f1[0] * w; acc[5] += f1[1] * w;
                acc[6] += f1[2] * w; acc[7] += f1[3] * w;
            }
        }
        #pragma unroll
        for (int n = 0; n < 8; ++n) part[g][n][h] = acc[n];
    }
    __syncthreads();

    // final reduce + hi/lo bf16 pack
    {
        const int h = p;
        const int na = t >> 8;
        const int ks = h >> 5, quad = (h >> 3) & 3, j = h & 7;
        const int nt = c >> 1;
        #pragma unroll
        for (int k = 0; k < 2; ++k) {
            const int nl = na + k * 4;
            const int n = c * 8 + nl;
            float f = part[0][nl][h] + part[1][nl][h] + part[2][nl][h] + part[3][nl][h];
            if (n >= NQ) f = 0.f;
            const u16 hi = f2bf(f);
            const u16 lo = f2bf(f - bf2f(hi));
            const int nit = (c & 1) * 8 + nl;
            const int lane2 = quad * 16 + nit;
            const size_t base = ((((size_t)b * 2 + 0) * 8 + ks) * 8 + nt) * 512 + lane2 * 8 + j;
            pack[base] = hi;
            pack[base + (size_t)8 * 8 * 512] = lo;
        }
    }
}

// ---------------------------------------------------------------------------
// K2 v10: R5 structure + T3/T4 proper. 3-deep LDS ring (3 x 16KB = 48KB ->
// 3 blocks/CU, was 28KB/"2 resident"); stage ks+2 each iter (2 compute
// phases of latency tolerance, was <1); in-loop sync = per-wave
// s_waitcnt vmcnt(4) + raw s_barrier (newest stage batch stays in flight
// across the barrier -- NEVER vmcnt(0) in-loop; that full drain was R3-R5's
// stall). Staging padded to 16 slots (nt=7 = allocated-but-unread pack
// space) so every wave issues exactly 4 DMA loads/iter -> uniform vmcnt(4).
// Race audit: stage(ks+2) writes slot (ks-1)%3 whose readers finished
// before barrier B_{ks-1}; readers of slot ks%3 protected by prev iter's
// counted wait + barrier. Tail: ks=6 waits vmcnt(0) to force stage(7);
// ks=7 has no barrier.
// ---------------------------------------------------------------------------
__global__ __launch_bounds__(256, 3) void ksim(
    const float* __restrict__ qf,    // [6400][16][256] f32
    const u16* __restrict__ pack,
    const float* __restrict__ cvec,
    float* __restrict__ sim)         // -> out + 3200, [16][100][6400] f32
{
    const int mc = blockIdx.x;  // 0..99  (64 rows each)
    const int b  = blockIdx.y;  // 0..15
    const int wv = threadIdx.x >> 6;
    const int lane = threadIdx.x & 63;
    const int quad = lane >> 4, l16 = lane & 15;

    // ring of 3 buffers; each: 16 slots (s14 = s*8+nt; nt=7 staged, never read)
    __shared__ __align__(16) u16 sbuf[3][16][512];   // 48 KB

    const u16* pbase = pack + (size_t)b * 65536;

    // each wave stages exactly 4 slots: s14 = wv*4 .. wv*4+3
    #define STAGE(KS, SLOT)                                                         \
        do {                                                                        \
            _Pragma("unroll")                                                       \
            for (int i = 0; i < 4; ++i) {                                           \
                const int s14 = wv * 4 + i;                                         \
                const int s_ = s14 >> 3, nt_ = s14 & 7;                             \
                const u16* g_ = pbase + ((size_t)(s_ * 8 + (KS)) * 8 + nt_) * 512   \
                                + (size_t)lane * 8;                                 \
                __builtin_amdgcn_global_load_lds(                                   \
                    (const __attribute__((address_space(1))) void*)g_,              \
                    (__attribute__((address_space(3))) void*)&sbuf[SLOT][s14][0],   \
                    16, 0, 0);                                                      \
            }                                                                       \
        } while (0)

    f32x4 acc[7];
    #pragma unroll
    for (int nt = 0; nt < 7; ++nt) acc[nt] = (f32x4){0.f, 0.f, 0.f, 0.f};

    const int row = mc * 64 + wv * 16 + l16;
    const float* ap = qf + (size_t)row * (BSZ * HID) + b * HID + quad * 8;

    // ---- prologue: 16 A loads in ONE asm block (un-sinkable, waits vmcnt 0),
    // then stage ks=0,1 into ring slots 0,1; __syncthreads drains the stages.
    f32x4 af[16];
    {
        const float* p0 = ap + 0 * 32;
        const float* p1 = ap + 1 * 32;
        const float* p2 = ap + 2 * 32;
        const float* p3 = ap + 3 * 32;
        const float* p4 = ap + 4 * 32;
        const float* p5 = ap + 5 * 32;
        const float* p6 = ap + 6 * 32;
        const float* p7 = ap + 7 * 32;
        asm volatile(
            "global_load_dwordx4 %0, %16, off\n\t"
            "global_load_dwordx4 %1, %16, off offset:16\n\t"
            "global_load_dwordx4 %2, %17, off\n\t"
            "global_load_dwordx4 %3, %17, off offset:16\n\t"
            "global_load_dwordx4 %4, %18, off\n\t"
            "global_load_dwordx4 %5, %18, off offset:16\n\t"
            "global_load_dwordx4 %6, %19, off\n\t"
            "global_load_dwordx4 %7, %19, off offset:16\n\t"
            "global_load_dwordx4 %8, %20, off\n\t"
            "global_load_dwordx4 %9, %20, off offset:16\n\t"
            "global_load_dwordx4 %10, %21, off\n\t"
            "global_load_dwordx4 %11, %21, off offset:16\n\t"
            "global_load_dwordx4 %12, %22, off\n\t"
            "global_load_dwordx4 %13, %22, off offset:16\n\t"
            "global_load_dwordx4 %14, %23, off\n\t"
            "global_load_dwordx4 %15, %23, off offset:16\n\t"
            "s_waitcnt vmcnt(0)"
            : "=&v"(af[0]), "=&v"(af[1]), "=&v"(af[2]), "=&v"(af[3]),
              "=&v"(af[4]), "=&v"(af[5]), "=&v"(af[6]), "=&v"(af[7]),
              "=&v"(af[8]), "=&v"(af[9]), "=&v"(af[10]), "=&v"(af[11]),
              "=&v"(af[12]), "=&v"(af[13]), "=&v"(af[14]), "=&v"(af[15])
            : "v"(p0), "v"(p1), "v"(p2), "v"(p3),
              "v"(p4), "v"(p5), "v"(p6), "v"(p7));
    }
    STAGE(0, 0);
    STAGE(1, 1);

    // convert A to hi/lo bf16 fragments (af dies here)
    bf16x8 Ahi[8], Alo[8];
    #pragma unroll
    for (int ks = 0; ks < 8; ++ks) {
        #pragma unroll
        for (int j = 0; j < 4; ++j) {
            const float v0 = af[2 * ks][j];
            const __bf16 h0 = (__bf16)v0;
            Ahi[ks][j] = h0; Alo[ks][j] = (__bf16)(v0 - (float)h0);
            const float v1 = af[2 * ks + 1][j];
            const __bf16 h1 = (__bf16)v1;
            Ahi[ks][4 + j] = h1; Alo[ks][4 + j] = (__bf16)(v1 - (float)h1);
        }
    }
    __syncthreads();   // drains stage(0),(1); full drain OK once in prologue

    // counted-vmcnt barrier: newest stage batch (4 loads) stays in flight
    #define WAITBAR(N)                                                              \
        do {                                                                        \
            asm volatile("s_waitcnt vmcnt(" #N ")" ::: "memory");                   \
            __builtin_amdgcn_sched_barrier(0);                                      \
            __builtin_amdgcn_s_barrier();                                           \
            __builtin_amdgcn_sched_barrier(0);                                      \
        } while (0)

    #define KS_BODY(KS, SR, SW, DOSTAGE)                                             \
    {                                                                                \
        if (DOSTAGE) STAGE((KS) + 2, SW);                                            \
        u16x8 uh[7];                                                                 \
        _Pragma("unroll")                                                            \
        for (int nt = 0; nt < 7; ++nt)                                               \
            uh[nt] = *reinterpret_cast<const u16x8*>(&sbuf[SR][nt][lane * 8]);       \
        _Pragma("unroll")                                                            \
        for (int nt = 0; nt < 7; ++nt) {                                             \
            const bf16x8 bh = __builtin_bit_cast(bf16x8, uh[nt]);                    \
            acc[nt] = __builtin_amdgcn_mfma_f32_16x16x32_bf16(Ahi[KS], bh, acc[nt], 0, 0, 0); \
            acc[nt] = __builtin_amdgcn_mfma_f32_16x16x32_bf16(Alo[KS], bh, acc[nt], 0, 0, 0); \
        }                                                                            \
        u16x8 ul[7];                                                                 \
        _Pragma("unroll")                                                            \
        for (int nt = 0; nt < 7; ++nt)                                               \
            ul[nt] = *reinterpret_cast<const u16x8*>(&sbuf[SR][8 + nt][lane * 8]);   \
        _Pragma("unroll")                                                            \
        for (int nt = 0; nt < 7; ++nt) {                                             \
            const bf16x8 bl = __builtin_bit_cast(bf16x8, ul[nt]);                    \
            acc[nt] = __builtin_amdgcn_mfma_f32_16x16x32_bf16(Ahi[KS], bl, acc[nt], 0, 0, 0); \
        }                                                                            \
    }

    KS_BODY(0, 0, 2, 1) WAITBAR(4);
    KS_BODY(1, 1, 0, 1) WAITBAR(4);
    KS_BODY(2, 2, 1, 1) WAITBAR(4);
    KS_BODY(3, 0, 2, 1) WAITBAR(4);
    KS_BODY(4, 1, 0, 1) WAITBAR(4);
    KS_BODY(5, 2, 1, 1) WAITBAR(4);
    KS_BODY(6, 0, 2, 0) WAITBAR(0);   // force stage(7) (issued at ks=5) complete
    KS_BODY(7, 1, 0, 0)               // last tile: no stage, no barrier

    #undef KS_BODY
    #undef WAITBAR
    #undef STAGE

    // epilogue: D row (k-dim) = quad*4 + r, col (n) = l16
    const int kbase = mc * 64 + wv * 16 + quad * 4;
    #pragma unroll
    for (int nt = 0; nt < 7; ++nt) {
        const int n = nt * 16 + l16;
        if (n >= NQ) continue;
        const float cadd = cvec[b * NQ + n];
        f32x4 o = acc[nt];
        o[0] += cadd; o[1] += cadd; o[2] += cadd; o[3] += cadd;
        *reinterpret_cast<f32x4*>(sim + (size_t)(b * NQ + n) * HWD + kbase) = o;
    }
}

// ---------------------------------------------------------------------------
// K3 v6 (unchanged): two waves per (b,n) row, pinned load batch.
// ---------------------------------------------------------------------------
__global__ __launch_bounds__(128, 2) void kfin(
    const float* __restrict__ sim,   // out + 3200
    float* __restrict__ out)         // f32 outputs, concatenated
{
    const int bn = blockIdx.x;       // 0..1599
    const int w = threadIdx.x >> 6;  // 0..1
    const int lane = threadIdx.x & 63;
    const float* src = sim + (size_t)bn * HWD;

    __shared__ float redf[2][8];

    const int base = w ? 12 : 0;
    const int cnt  = w ? 13 : 12;

    f32x4 v[13];
    #pragma unroll
    for (int j = 0; j < 13; ++j)
        if (j < cnt)
            v[j] = *reinterpret_cast<const f32x4*>(src + (base + j) * 256 + lane * 4);
    __builtin_amdgcn_sched_barrier(0);

    // phase A: local max / first-occurrence argmax, then global via LDS
    float bv = -3.4e38f; int bi = 0x7FFFFFFF;
    #pragma unroll
    for (int j = 0; j < 13; ++j) {
        if (j < cnt) {
            #pragma unroll
            for (int k = 0; k < 4; ++k) {
                if (v[j][k] > bv) { bv = v[j][k]; bi = (base + j) * 256 + lane * 4 + k; }
            }
        }
    }
    #pragma unroll
    for (int m = 1; m < 64; m <<= 1) {
        const float ov = __shfl_xor(bv, m);
        const int oi = __shfl_xor(bi, m);
        if (ov > bv || (ov == bv && oi < bi)) { bv = ov; bi = oi; }
    }
    if (lane == 0) { redf[w][0] = bv; redf[w][1] = __int_as_float(bi); }
    __syncthreads();
    {
        const float v0 = redf[0][0], v1 = redf[1][0];
        const int i0 = __float_as_int(redf[0][1]), i1 = __float_as_int(redf[1][1]);
        if (v1 > v0 || (v1 == v0 && i1 < i0)) { bv = v1; bi = i1; }
        else { bv = v0; bi = i0; }
    }
    const int xc = bi % WW, yc = bi / WW;

    // phase B: exp sums + 3x3 window sums
    float s1 = 0.f, sx = 0.f, sy = 0.f;
    float wl = 0.f, wx = 0.f, wyv = 0.f;
    const int g0 = base * 256 + lane * 4;
    int x = g0 % WW, y = g0 / WW;
    #pragma unroll
    for (int j = 0; j < 13; ++j) {
        if (j < cnt) {
            #pragma unroll
            for (int k = 0; k < 4; ++k) {
                int xe = x + k, ye = y;
                if (xe >= WW) { xe -= WW; ye += 1; }
                const float e = __expf(v[j][k] - bv);
                const float fx = (float)xe + 0.5f;
                const float fy = (float)ye + 0.5f;
                s1 += e; sx += e * fx; sy += e * fy;
                const int dx = xe - xc, dy = ye - yc;
                const bool inw = (dx >= -1 && dx <= 1 && dy >= -1 && dy <= 1);
                const float ew = inw ? e : 0.f;
                wl += ew; wx += ew * fx; wyv += ew * fy;
            }
        }
        x += 16; y += 3;
        if (x >= WW) { x -= WW; y += 1; }
    }
    #pragma unroll
    for (int m = 1; m < 64; m <<= 1) {
        s1 += __shfl_xor(s1, m);
        sx += __shfl_xor(sx, m);
        sy += __shfl_xor(sy, m);
        wl += __shfl_xor(wl, m);
        wx += __shfl_xor(wx, m);
        wyv += __shfl_xor(wyv, m);
    }
    if (lane == 0) {
        redf[w][2] = s1; redf[w][3] = sx; redf[w][4] = sy;
        redf[w][5] = wl; redf[w][6] = wx; redf[w][7] = wyv;
    }
    __syncthreads();

    if (w == 0 && lane == 0) {
        const float S1 = redf[0][2] + redf[1][2];
        const float SX = redf[0][3] + redf[1][3];
        const float SY = redf[0][4] + redf[1][4];
        const float WL = redf[0][5] + redf[1][5];
        const float WX = redf[0][6] + redf[1][6];
        const float WY = redf[0][7] + redf[1][7];
        const float invS = 1.f / S1;
        out[(size_t)bn * 2 + 0] = SX * invS / (float)WW;
        out[(size_t)bn * 2 + 1] = SY * invS / (float)HH;
        const float den = WL + 1e-10f * S1;
        const size_t pbase = 3200 + (size_t)BSZ * NQ * HWD;
        out[pbase + (size_t)bn * 2 + 0] = WX / den / (float)WW;
        out[pbase + (size_t)bn * 2 + 1] = WY / den / (float)HH;
    }
}

extern "C" void kernel_launch(void* const* d_in, const int* in_sizes, int n_in,
                              void* d_out, int out_size, void* d_ws, size_t ws_size,
                              hipStream_t stream) {
    const float* qf  = (const float*)d_in[0];   // query_feat  [6400][16][256] f32
    const float* sf  = (const float*)d_in[1];   // support_feat[100][16][256] f32
    // d_in[2], d_in[3] = h, w (fixed 80x80)
    const float* Wq  = (const float*)d_in[4];
    const float* bq  = (const float*)d_in[5];
    const float* Ws  = (const float*)d_in[6];
    const float* bsp = (const float*)d_in[7];
    const float* W1  = (const float*)d_in[8];
    const float* b1  = (const float*)d_in[9];
    const float* W2  = (const float*)d_in[10];
    const float* b2  = (const float*)d_in[11];

    u16*   pack  = (u16*)d_ws;                         // 2,097,152 B
    float* cvec  = (float*)((char*)d_ws + 2097152);    //     6,400 B
    float* out   = (float*)d_out;
    float* sim   = out + 3200;                         // similarity region, f32

    kpre<<<dim3(14, 16), 1024, 0, stream>>>(sf, Wq, bq, Ws, bsp, W1, b1, W2, b2, pack, cvec);
    ksim<<<dim3(100, 16), 256, 0, stream>>>(qf, pack, cvec, sim);
    kfin<<<1600, 64 * 2, 0, stream>>>(sim, out);
}